// Round 4
// baseline (166.809 us; speedup 1.0000x reference)
//
#include <hip/hip_runtime.h>

#define BB 2
#define HH 1024
#define WW 1024
#define MU 5

// fused-pass tile geometry
#define TH 32
#define TW 64
#define SW (TW + 16)        // 80 staged cols (8-col halo each side, float4-aligned)
#define SH (TH + 2 * MU)    // 42 staged rows

__device__ __forceinline__ float fast_rcp(float x) { return __builtin_amdgcn_rcpf(x); }
__device__ __forceinline__ float fast_rsq(float x) { return __builtin_amdgcn_rsqf(x); }
// (tanh(d)+1)/2 == 1/(1+exp(-2d)); the 2/gmax scale is folded by the caller
__device__ __forceinline__ float sigm(float x) { return fast_rcp(1.f + __expf(-x)); }

// ---------------------------------------------------------------------------
// Kernel 1: Sobel + init tangent (INTERLEAVED (B,H,W,2)) + raw mag + block max.
// 8 rows x 256 cols per block -> 1024 blocks, 10.6 KB LDS (full occupancy).
// ---------------------------------------------------------------------------
#define SR 8
__global__ __launch_bounds__(256) void sobel_init(
    const float* __restrict__ x,
    float* __restrict__ tf,          // (B,H,W,2) interleaved
    float* __restrict__ mag,         // (B,H,W) raw
    float* __restrict__ block_max)   // 1024
{
    __shared__ float xs[SR + 2][264];     // cols w0-4 .. w0+259, zero OOB
    const int t = threadIdx.x;
    const int w0 = blockIdx.x * 256;
    const int h0 = blockIdx.y * SR;
    const int b = blockIdx.z;
    const size_t plane = (size_t)HH * WW;
    const float* xb = x + (size_t)b * plane;

    for (int i = t; i < (SR + 2) * 66; i += 256) {
        int r = i / 66, c4 = i % 66;
        int g = h0 - 1 + r;
        int gw = w0 - 4 + 4 * c4;
        float4 v = make_float4(0.f, 0.f, 0.f, 0.f);
        if (g >= 0 && g < HH && gw >= 0 && gw < WW)
            v = *(const float4*)(xb + (size_t)g * WW + gw);
        *(float4*)&xs[r][4 * c4] = v;
    }
    __syncthreads();

    float lmax = 0.f;
    const int c = 4 + t;
    #pragma unroll
    for (int k = 0; k < SR; ++k) {
        const float* rT = xs[k], * rM = xs[k + 1], * rB = xs[k + 2];
        float tl = rT[c - 1], tc = rT[c], tr = rT[c + 1];
        float ml = rM[c - 1],             mr = rM[c + 1];
        float bl = rB[c - 1], bc = rB[c], br = rB[c + 1];
        float s0 = (bl - tl) + 2.f * (bc - tc) + (br - tr);   // k
        float s1 = (tr - tl) + 2.f * (mr - ml) + (br - bl);   // k^T
        float m = sqrtf(fmaf(s0, s0, s1 * s1));
        float inv = (m == 0.f) ? 1.f : fast_rcp(m);
        size_t gi = (size_t)(h0 + k) * WW + (w0 + t);
        mag[(size_t)b * plane + gi] = m;
        ((float2*)tf)[(size_t)b * plane + gi] = make_float2(-s1 * inv, s0 * inv);
        lmax = fmaxf(lmax, m);
    }

    #pragma unroll
    for (int off = 32; off; off >>= 1) lmax = fmaxf(lmax, __shfl_down(lmax, off, 64));
    __shared__ float smax[4];
    if ((t & 63) == 0) smax[t >> 6] = lmax;
    __syncthreads();
    if (t == 0)
        block_max[(blockIdx.z * 128 + blockIdx.y) * 4 + blockIdx.x] =
            fmaxf(fmaxf(smax[0], smax[1]), fmaxf(smax[2], smax[3]));
}

// ---------------------------------------------------------------------------
// Kernel 2: reduce 1024 per-block maxes -> gmax.
// ---------------------------------------------------------------------------
__global__ __launch_bounds__(256) void reduce_max(
    const float* __restrict__ block_max, float* __restrict__ gmax)
{
    const int t = threadIdx.x;
    float m = 0.f;
    #pragma unroll
    for (int i = 0; i < 4; ++i) m = fmaxf(m, block_max[t + 256 * i]);
    #pragma unroll
    for (int off = 32; off; off >>= 1) m = fmaxf(m, __shfl_down(m, off, 64));
    __shared__ float smax[4];
    if ((t & 63) == 0) smax[t >> 6] = m;
    __syncthreads();
    if (t == 0) gmax[0] = fmaxf(fmaxf(smax[0], smax[1]), fmaxf(smax[2], smax[3]));
}

// ---------------------------------------------------------------------------
// Kernel 3: FUSED Vertical+Horizontal ETF pass.
// Stage (42x80) tang(interleaved)+mag in LDS; V -> 32x80 LDS intermediate
// (covers H's +-5 col halo); barrier; H -> 32x64 output tile.
// Zero-staged OOB px reproduce reference zero-padding exactly (contribution 0,
// and normalize(0)=0 matches _normalize's mag==0 -> 1 guard).
// LDS = 26880 + 13440 + 20480 = 60.8 KB -> 2 blocks/CU.
// ---------------------------------------------------------------------------
template <int PLANAR_OUT>
__global__ __launch_bounds__(256) void etf_vh(
    const float* __restrict__ tin,   // (B,H,W,2) interleaved
    float* __restrict__ tout,        // interleaved, or planar (B,2,H,W) if PLANAR_OUT
    const float* __restrict__ mag,
    const float* __restrict__ gmax)
{
    __shared__ float st[SH * SW * 2];   // staged tang, addr = px*2 (linear in px)
    __shared__ float sm[SH * SW];       // staged mag
    __shared__ float sv[TH * SW * 2];   // V results (normalized)
    const int t = threadIdx.x;
    const int w0 = blockIdx.x * TW;
    const int h0 = blockIdx.y * TH;
    const int b = blockIdx.z;
    const size_t plane = (size_t)HH * WW;
    const float* tb = tin + 2 * (size_t)b * plane;
    const float* mb = mag + (size_t)b * plane;

    // stage-in: tang = 42*40 float4 chunks (2 px), mag = 42*20 chunks (4 px)
    for (int i = t; i < SH * 40 + SH * 20; i += 256) {
        if (i < SH * 40) {
            int r = i / 40, c4 = i % 40;
            int g = h0 - MU + r;
            int gw = w0 - 8 + 2 * c4;
            float4 v = make_float4(0.f, 0.f, 0.f, 0.f);
            if (g >= 0 && g < HH && gw >= 0 && gw < WW)
                v = *(const float4*)(tb + 2 * ((size_t)g * WW + gw));
            *(float4*)&st[r * SW * 2 + 4 * c4] = v;
        } else {
            int j = i - SH * 40;
            int r = j / 20, c4 = j % 20;
            int g = h0 - MU + r;
            int gw = w0 - 8 + 4 * c4;
            float4 v = make_float4(0.f, 0.f, 0.f, 0.f);
            if (g >= 0 && g < HH && gw >= 0 && gw < WW)
                v = *(const float4*)(mb + (size_t)g * WW + gw);
            *(float4*)&sm[r * SW + 4 * c4] = v;
        }
    }
    __syncthreads();

    const float s2 = 2.f * fast_rcp(gmax[0]);

    // ---- V phase: 32 x 80 px, 10 px/thread (addr linear in px -> no conflicts)
    #pragma unroll
    for (int k = 0; k < 10; ++k) {
        int px = t + 256 * k;
        int r = px / SW, c = px % SW;
        float2 tx = *(const float2*)&st[((r + MU) * SW + c) * 2];
        float mx = sm[(r + MU) * SW + c];
        float a0 = 0.f, a1 = 0.f;
        #pragma unroll
        for (int d = 0; d <= 2 * MU; ++d) {
            float2 ty = *(const float2*)&st[((r + d) * SW + c) * 2];
            float my = sm[(r + d) * SW + c];
            float dt = fmaf(tx.x, ty.x, tx.y * ty.y);
            float w = sigm(s2 * (my - mx)) * dt;
            a0 = fmaf(ty.x, w, a0);
            a1 = fmaf(ty.y, w, a1);
        }
        float n2 = fmaf(a0, a0, a1 * a1);
        float inv = (n2 == 0.f) ? 1.f : fast_rsq(n2);
        *(float2*)&sv[px * 2] = make_float2(a0 * inv, a1 * inv);
    }
    __syncthreads();

    // ---- H phase: 32 x 64 px, 8 px/thread; sv cols 3..76 in range
    #pragma unroll
    for (int k = 0; k < 8; ++k) {
        int px = t + 256 * k;
        int r = px >> 6, c = px & 63;
        int sc = c + 8;
        float2 tx = *(const float2*)&sv[(r * SW + sc) * 2];
        float mx = sm[(r + MU) * SW + sc];
        float a0 = 0.f, a1 = 0.f;
        #pragma unroll
        for (int d = -MU; d <= MU; ++d) {
            float2 ty = *(const float2*)&sv[(r * SW + sc + d) * 2];
            float my = sm[(r + MU) * SW + sc + d];
            float dt = fmaf(tx.x, ty.x, tx.y * ty.y);
            float w = sigm(s2 * (my - mx)) * dt;
            a0 = fmaf(ty.x, w, a0);
            a1 = fmaf(ty.y, w, a1);
        }
        float n2 = fmaf(a0, a0, a1 * a1);
        float inv = (n2 == 0.f) ? 1.f : fast_rsq(n2);
        size_t gi = (size_t)(h0 + r) * WW + (w0 + c);
        if (PLANAR_OUT) {
            tout[(size_t)(2 * b)     * plane + gi] = a0 * inv;
            tout[(size_t)(2 * b + 1) * plane + gi] = a1 * inv;
        } else {
            *(float2*)&tout[2 * ((size_t)b * plane + gi)] = make_float2(a0 * inv, a1 * inv);
        }
    }
}

extern "C" void kernel_launch(void* const* d_in, const int* in_sizes, int n_in,
                              void* d_out, int out_size, void* d_ws, size_t ws_size,
                              hipStream_t stream)
{
    const float* x = (const float*)d_in[0];   // (2,1,1024,1024) fp32
    char* ws = (char*)d_ws;
    const size_t plane = (size_t)HH * WW;

    float* tfA  = (float*)ws;                                           // 16 MB interleaved
    float* tfB  = (float*)(ws + sizeof(float) * BB * 2 * plane);        // 16 MB interleaved
    float* mag  = (float*)(ws + sizeof(float) * BB * 4 * plane);        // 8 MB
    float* gmax = (float*)(ws + sizeof(float) * BB * 6 * plane);        // 4 B
    float* block_max = gmax + 16;                                       // 1024 floats

    sobel_init<<<dim3(4, 128, BB), 256, 0, stream>>>(x, tfA, mag, block_max);
    reduce_max<<<1, 256, 0, stream>>>(block_max, gmax);

    dim3 g(WW / TW, HH / TH, BB);
    etf_vh<0><<<g, 256, 0, stream>>>(tfA, tfB, mag, gmax);
    etf_vh<0><<<g, 256, 0, stream>>>(tfB, tfA, mag, gmax);
    etf_vh<1><<<g, 256, 0, stream>>>(tfA, (float*)d_out, mag, gmax);
}

// Round 5
// 147.195 us; speedup vs baseline: 1.1333x; 1.1333x over previous
//
#include <hip/hip_runtime.h>

#define BB 2
#define HH 1024
#define WW 1024
#define MU 5

// fused-pass tile geometry
#define TH 32
#define TW 64
#define SW (TW + 16)        // 80 staged cols (8-col halo each side, float4-aligned)
#define SH (TH + 2 * MU)    // 42 staged rows

__device__ __forceinline__ float fast_rcp(float x) { return __builtin_amdgcn_rcpf(x); }
__device__ __forceinline__ float fast_rsq(float x) { return __builtin_amdgcn_rsqf(x); }

// ---------------------------------------------------------------------------
// Kernel 1: Sobel + init tangent (INTERLEAVED (B,H,W,2)) + raw mag + block max.
// ---------------------------------------------------------------------------
#define SR 8
__global__ __launch_bounds__(256) void sobel_init(
    const float* __restrict__ x,
    float* __restrict__ tf,          // (B,H,W,2) interleaved
    float* __restrict__ mag,         // (B,H,W) raw
    float* __restrict__ block_max)   // 1024
{
    __shared__ float xs[SR + 2][264];     // cols w0-4 .. w0+259, zero OOB
    const int t = threadIdx.x;
    const int w0 = blockIdx.x * 256;
    const int h0 = blockIdx.y * SR;
    const int b = blockIdx.z;
    const size_t plane = (size_t)HH * WW;
    const float* xb = x + (size_t)b * plane;

    for (int i = t; i < (SR + 2) * 66; i += 256) {
        int r = i / 66, c4 = i % 66;
        int g = h0 - 1 + r;
        int gw = w0 - 4 + 4 * c4;
        float4 v = make_float4(0.f, 0.f, 0.f, 0.f);
        if (g >= 0 && g < HH && gw >= 0 && gw < WW)
            v = *(const float4*)(xb + (size_t)g * WW + gw);
        *(float4*)&xs[r][4 * c4] = v;
    }
    __syncthreads();

    float lmax = 0.f;
    const int c = 4 + t;
    #pragma unroll
    for (int k = 0; k < SR; ++k) {
        const float* rT = xs[k], * rM = xs[k + 1], * rB = xs[k + 2];
        float tl = rT[c - 1], tc = rT[c], tr = rT[c + 1];
        float ml = rM[c - 1],             mr = rM[c + 1];
        float bl = rB[c - 1], bc = rB[c], br = rB[c + 1];
        float s0 = (bl - tl) + 2.f * (bc - tc) + (br - tr);   // k
        float s1 = (tr - tl) + 2.f * (mr - ml) + (br - bl);   // k^T
        float m = sqrtf(fmaf(s0, s0, s1 * s1));
        float inv = (m == 0.f) ? 1.f : fast_rcp(m);
        size_t gi = (size_t)(h0 + k) * WW + (w0 + t);
        mag[(size_t)b * plane + gi] = m;
        ((float2*)tf)[(size_t)b * plane + gi] = make_float2(-s1 * inv, s0 * inv);
        lmax = fmaxf(lmax, m);
    }

    #pragma unroll
    for (int off = 32; off; off >>= 1) lmax = fmaxf(lmax, __shfl_down(lmax, off, 64));
    __shared__ float smax[4];
    if ((t & 63) == 0) smax[t >> 6] = lmax;
    __syncthreads();
    if (t == 0)
        block_max[(blockIdx.z * 128 + blockIdx.y) * 4 + blockIdx.x] =
            fmaxf(fmaxf(smax[0], smax[1]), fmaxf(smax[2], smax[3]));
}

// ---------------------------------------------------------------------------
// Kernel 2: reduce 1024 per-block maxes -> gmax.
// ---------------------------------------------------------------------------
__global__ __launch_bounds__(256) void reduce_max(
    const float* __restrict__ block_max, float* __restrict__ gmax)
{
    const int t = threadIdx.x;
    float m = 0.f;
    #pragma unroll
    for (int i = 0; i < 4; ++i) m = fmaxf(m, block_max[t + 256 * i]);
    #pragma unroll
    for (int off = 32; off; off >>= 1) m = fmaxf(m, __shfl_down(m, off, 64));
    __shared__ float smax[4];
    if ((t & 63) == 0) smax[t >> 6] = m;
    __syncthreads();
    if (t == 0) gmax[0] = fmaxf(fmaxf(smax[0], smax[1]), fmaxf(smax[2], smax[3]));
}

// ---------------------------------------------------------------------------
// Kernel 3: mag -> em = exp(-2*mag/max), in place. mag is only ever consumed
// through (tanh(my-mx)+1)/2 == 1/(1 + em_y / em_x), so em replaces it.
// ---------------------------------------------------------------------------
__global__ __launch_bounds__(256) void mag2em(
    float* __restrict__ mag, const float* __restrict__ gmax)
{
    const float s = 2.f * fast_rcp(gmax[0]);
    const int i = blockIdx.x * 256 + threadIdx.x;
    float4* p = (float4*)mag + i;
    float4 v = *p;
    v.x = __expf(-s * v.x);
    v.y = __expf(-s * v.y);
    v.z = __expf(-s * v.z);
    v.w = __expf(-s * v.w);
    *p = v;
}

// ---------------------------------------------------------------------------
// Kernel 4: FUSED Vertical+Horizontal ETF pass, em-weights, aliased LDS.
//   lds[0..6720)      staged tang (42x80 px, float2)    -- dead after V phase
//   lds[6720..10080)  staged em   (42x80 px)
//   lds[0..5120)      V results   (32x80 px, float2)    -- aliases staged tang
// V results computed into registers, barrier, written into alias, barrier, H.
// LDS = 40320 B -> 4 blocks/CU (16 waves/CU).
// OOB stage: tang=0 (exact zero-pad), em=1.0 (finite weights; ty=0 kills
// contribution, matching reference zero-pad; avoids rcp(0) NaN at edges).
// ---------------------------------------------------------------------------
template <int PLANAR_OUT>
__global__ __launch_bounds__(256) void etf_vh(
    const float* __restrict__ tin,   // (B,H,W,2) interleaved
    float* __restrict__ tout,        // interleaved, or planar (B,2,H,W) if PLANAR_OUT
    const float* __restrict__ em)    // (B,H,W)
{
    __shared__ float lds[SH * SW * 3];          // 40320 B
    float* st = lds;                            // staged tang (float2 per px)
    float* sm = lds + SH * SW * 2;              // staged em
    float* sv = lds;                            // V results (aliases st)

    const int t = threadIdx.x;
    const int w0 = blockIdx.x * TW;
    const int h0 = blockIdx.y * TH;
    const int b = blockIdx.z;
    const size_t plane = (size_t)HH * WW;
    const float* tb = tin + 2 * (size_t)b * plane;
    const float* mb = em + (size_t)b * plane;

    // stage-in: tang = 42*40 float4 chunks (2 px), em = 42*20 chunks (4 px)
    for (int i = t; i < SH * 40 + SH * 20; i += 256) {
        if (i < SH * 40) {
            int r = i / 40, c4 = i % 40;
            int g = h0 - MU + r;
            int gw = w0 - 8 + 2 * c4;
            float4 v = make_float4(0.f, 0.f, 0.f, 0.f);
            if (g >= 0 && g < HH && gw >= 0 && gw < WW)
                v = *(const float4*)(tb + 2 * ((size_t)g * WW + gw));
            *(float4*)&st[r * SW * 2 + 4 * c4] = v;
        } else {
            int j = i - SH * 40;
            int r = j / 20, c4 = j % 20;
            int g = h0 - MU + r;
            int gw = w0 - 8 + 4 * c4;
            float4 v = make_float4(1.f, 1.f, 1.f, 1.f);
            if (g >= 0 && g < HH && gw >= 0 && gw < WW)
                v = *(const float4*)(mb + (size_t)g * WW + gw);
            *(float4*)&sm[r * SW + 4 * c4] = v;
        }
    }
    __syncthreads();

    // ---- V phase: 32 x 80 px, 10 px/thread, results to registers
    float vr0[10], vr1[10];
    #pragma unroll
    for (int k = 0; k < 10; ++k) {
        int px = t + 256 * k;
        int r = px / SW, c = px % SW;
        float2 tx = *(const float2*)&st[((r + MU) * SW + c) * 2];
        float remx = fast_rcp(sm[(r + MU) * SW + c]);
        float a0 = 0.f, a1 = 0.f;
        #pragma unroll
        for (int d = 0; d <= 2 * MU; ++d) {
            float2 ty = *(const float2*)&st[((r + d) * SW + c) * 2];
            float emy = sm[(r + d) * SW + c];
            float s = fast_rcp(fmaf(emy, remx, 1.f));       // (tanh(my-mx)+1)/2
            float w = s * fmaf(tx.x, ty.x, tx.y * ty.y);
            a0 = fmaf(ty.x, w, a0);
            a1 = fmaf(ty.y, w, a1);
        }
        float n2 = fmaf(a0, a0, a1 * a1);
        float inv = (n2 == 0.f) ? 1.f : fast_rsq(n2);
        vr0[k] = a0 * inv;
        vr1[k] = a1 * inv;
    }
    __syncthreads();     // all reads of st complete
    #pragma unroll
    for (int k = 0; k < 10; ++k) {
        int px = t + 256 * k;
        *(float2*)&sv[px * 2] = make_float2(vr0[k], vr1[k]);
    }
    __syncthreads();

    // ---- H phase: 32 x 64 px, 8 px/thread; sv cols 3..76 in range
    #pragma unroll
    for (int k = 0; k < 8; ++k) {
        int px = t + 256 * k;
        int r = px >> 6, c = px & 63;
        int sc = c + 8;
        float2 tx = *(const float2*)&sv[(r * SW + sc) * 2];
        float remx = fast_rcp(sm[(r + MU) * SW + sc]);
        float a0 = 0.f, a1 = 0.f;
        #pragma unroll
        for (int d = -MU; d <= MU; ++d) {
            float2 ty = *(const float2*)&sv[(r * SW + sc + d) * 2];
            float emy = sm[(r + MU) * SW + sc + d];
            float s = fast_rcp(fmaf(emy, remx, 1.f));
            float w = s * fmaf(tx.x, ty.x, tx.y * ty.y);
            a0 = fmaf(ty.x, w, a0);
            a1 = fmaf(ty.y, w, a1);
        }
        float n2 = fmaf(a0, a0, a1 * a1);
        float inv = (n2 == 0.f) ? 1.f : fast_rsq(n2);
        size_t gi = (size_t)(h0 + r) * WW + (w0 + c);
        if (PLANAR_OUT) {
            tout[(size_t)(2 * b)     * plane + gi] = a0 * inv;
            tout[(size_t)(2 * b + 1) * plane + gi] = a1 * inv;
        } else {
            *(float2*)&tout[2 * ((size_t)b * plane + gi)] = make_float2(a0 * inv, a1 * inv);
        }
    }
}

extern "C" void kernel_launch(void* const* d_in, const int* in_sizes, int n_in,
                              void* d_out, int out_size, void* d_ws, size_t ws_size,
                              hipStream_t stream)
{
    const float* x = (const float*)d_in[0];   // (2,1,1024,1024) fp32
    char* ws = (char*)d_ws;
    const size_t plane = (size_t)HH * WW;

    float* tfA  = (float*)ws;                                           // 16 MB interleaved
    float* tfB  = (float*)(ws + sizeof(float) * BB * 2 * plane);        // 16 MB interleaved
    float* mag  = (float*)(ws + sizeof(float) * BB * 4 * plane);        // 8 MB (becomes em)
    float* gmax = (float*)(ws + sizeof(float) * BB * 6 * plane);        // 4 B
    float* block_max = gmax + 16;                                       // 1024 floats

    sobel_init<<<dim3(4, 128, BB), 256, 0, stream>>>(x, tfA, mag, block_max);
    reduce_max<<<1, 256, 0, stream>>>(block_max, gmax);
    mag2em<<<dim3(BB * plane / 1024), 256, 0, stream>>>(mag, gmax);

    dim3 g(WW / TW, HH / TH, BB);
    etf_vh<0><<<g, 256, 0, stream>>>(tfA, tfB, mag);
    etf_vh<0><<<g, 256, 0, stream>>>(tfB, tfA, mag);
    etf_vh<1><<<g, 256, 0, stream>>>(tfA, (float*)d_out, mag);
}

// Round 6
// 134.500 us; speedup vs baseline: 1.2402x; 1.0944x over previous
//
#include <hip/hip_runtime.h>

#define BB 2
#define HH 1024
#define WW 1024
#define MU 5

// fused-pass tile geometry
#define TH 32
#define TW 64
#define SH (TH + 2 * MU)   // 42 staged rows
#define SCW 80             // staged cols = TW + 16 (8-col halo each side)
#define SMS 83             // em LDS row stride (odd -> conflict-free H reads)
#define SVS 81             // V-result LDS row stride (odd -> conflict-free H reads)

__device__ __forceinline__ float fast_rcp(float x) { return __builtin_amdgcn_rcpf(x); }
__device__ __forceinline__ float fast_rsq(float x) { return __builtin_amdgcn_rsqf(x); }

// ---------------------------------------------------------------------------
// Kernel 1: Sobel + init tangent (interleaved (B,H,W,2)) + raw mag + block max.
// ---------------------------------------------------------------------------
#define SR 8
__global__ __launch_bounds__(256) void sobel_init(
    const float* __restrict__ x,
    float* __restrict__ tf,          // (B,H,W,2) interleaved
    float* __restrict__ mag,         // (B,H,W) raw
    float* __restrict__ block_max)   // 1024
{
    __shared__ float xs[SR + 2][264];
    const int t = threadIdx.x;
    const int w0 = blockIdx.x * 256;
    const int h0 = blockIdx.y * SR;
    const int b = blockIdx.z;
    const size_t plane = (size_t)HH * WW;
    const float* xb = x + (size_t)b * plane;

    for (int i = t; i < (SR + 2) * 66; i += 256) {
        int r = i / 66, c4 = i % 66;
        int g = h0 - 1 + r;
        int gw = w0 - 4 + 4 * c4;
        float4 v = make_float4(0.f, 0.f, 0.f, 0.f);
        if (g >= 0 && g < HH && gw >= 0 && gw < WW)
            v = *(const float4*)(xb + (size_t)g * WW + gw);
        *(float4*)&xs[r][4 * c4] = v;
    }
    __syncthreads();

    float lmax = 0.f;
    const int c = 4 + t;
    #pragma unroll
    for (int k = 0; k < SR; ++k) {
        const float* rT = xs[k], * rM = xs[k + 1], * rB = xs[k + 2];
        float tl = rT[c - 1], tc = rT[c], tr = rT[c + 1];
        float ml = rM[c - 1],             mr = rM[c + 1];
        float bl = rB[c - 1], bc = rB[c], br = rB[c + 1];
        float s0 = (bl - tl) + 2.f * (bc - tc) + (br - tr);   // k
        float s1 = (tr - tl) + 2.f * (mr - ml) + (br - bl);   // k^T
        float m = sqrtf(fmaf(s0, s0, s1 * s1));
        float inv = (m == 0.f) ? 1.f : fast_rcp(m);
        size_t gi = (size_t)(h0 + k) * WW + (w0 + t);
        mag[(size_t)b * plane + gi] = m;
        ((float2*)tf)[(size_t)b * plane + gi] = make_float2(-s1 * inv, s0 * inv);
        lmax = fmaxf(lmax, m);
    }

    #pragma unroll
    for (int off = 32; off; off >>= 1) lmax = fmaxf(lmax, __shfl_down(lmax, off, 64));
    __shared__ float smax[4];
    if ((t & 63) == 0) smax[t >> 6] = lmax;
    __syncthreads();
    if (t == 0)
        block_max[(blockIdx.z * 128 + blockIdx.y) * 4 + blockIdx.x] =
            fmaxf(fmaxf(smax[0], smax[1]), fmaxf(smax[2], smax[3]));
}

// ---------------------------------------------------------------------------
// Kernel 2: reduce 1024 per-block maxes -> gmax.
// ---------------------------------------------------------------------------
__global__ __launch_bounds__(256) void reduce_max(
    const float* __restrict__ block_max, float* __restrict__ gmax)
{
    const int t = threadIdx.x;
    float m = 0.f;
    #pragma unroll
    for (int i = 0; i < 4; ++i) m = fmaxf(m, block_max[t + 256 * i]);
    #pragma unroll
    for (int off = 32; off; off >>= 1) m = fmaxf(m, __shfl_down(m, off, 64));
    __shared__ float smax[4];
    if ((t & 63) == 0) smax[t >> 6] = m;
    __syncthreads();
    if (t == 0) gmax[0] = fmaxf(fmaxf(smax[0], smax[1]), fmaxf(smax[2], smax[3]));
}

// ---------------------------------------------------------------------------
// Kernel 3: FUSED V+H ETF pass, register sliding windows.
// Weight identity: (tanh(my-mx)+1)/2 = 1/(1 + em_y/em_x), em = exp(-2*mag/max),
// computed during staging from RAW mag (no separate em kernel/array).
// LDS: st (tang, 42x80 float2, stride 160 fl) + sm (em, 42 rows, stride 83 fl)
//      sv0/sv1 (V results, 32 rows, stride 81 fl) alias st after V phase.
// Total 40824 B -> 4 blocks/CU.
// OOB staging: tang=0, mag=0 -> em=1 (exact reference zero-pad semantics;
// contribution 0 via ty=0; rcp(1) finite).
// ---------------------------------------------------------------------------
template <int PLANAR_OUT>
__global__ __launch_bounds__(256, 4) void etf_vh(
    const float* __restrict__ tin,   // (B,H,W,2) interleaved
    float* __restrict__ tout,        // interleaved, or planar (B,2,H,W)
    const float* __restrict__ mag,   // (B,H,W) RAW
    const float* __restrict__ gmax)
{
    __shared__ float lds[SH * SCW * 2 + SH * SMS];   // 40824 B
    float* st  = lds;                 // staged tang, float2/px, row stride 160 floats
    float* sm  = lds + SH * SCW * 2;  // staged em, row stride SMS
    float* sv0 = lds;                 // V results plane 0 (aliases st)
    float* sv1 = lds + TH * SVS;      // V results plane 1

    const int t = threadIdx.x;
    const int w0 = blockIdx.x * TW;
    const int h0 = blockIdx.y * TH;
    const int b = blockIdx.z;
    const size_t plane = (size_t)HH * WW;
    const float* tb = tin + 2 * (size_t)b * plane;
    const float* mb = mag + (size_t)b * plane;
    const float s2 = 2.f * fast_rcp(gmax[0]);

    // ---- stage: tang 42x40 float4 (2px) chunks; em 42x20 float4 (4px) + exp
    for (int i = t; i < SH * 40 + SH * 20; i += 256) {
        if (i < SH * 40) {
            int r = i / 40, c4 = i % 40;
            int g = h0 - MU + r;
            int gw = w0 - 8 + 2 * c4;
            float4 v = make_float4(0.f, 0.f, 0.f, 0.f);
            if (g >= 0 && g < HH && gw >= 0 && gw < WW)
                v = *(const float4*)(tb + 2 * ((size_t)g * WW + gw));
            *(float4*)&st[r * (SCW * 2) + 4 * c4] = v;    // 16B-aligned
        } else {
            int j = i - SH * 40;
            int r = j / 20, c4 = j % 20;
            int g = h0 - MU + r;
            int gw = w0 - 8 + 4 * c4;
            float4 v = make_float4(0.f, 0.f, 0.f, 0.f);   // mag=0 -> em=1
            if (g >= 0 && g < HH && gw >= 0 && gw < WW)
                v = *(const float4*)(mb + (size_t)g * WW + gw);
            float* dst = &sm[r * SMS + 4 * c4];
            dst[0] = __expf(-s2 * v.x);
            dst[1] = __expf(-s2 * v.y);
            dst[2] = __expf(-s2 * v.z);
            dst[3] = __expf(-s2 * v.w);
        }
    }
    __syncthreads();

    // ---- V phase: 240 threads = 80 cols x 3 row-strips {11,11,10}.
    // Load whole (R+10)-value window into registers, then compute centers.
    float w0r[21], w1r[21], wer[21];
    const int c = t % 80;
    const int strip = t / 80;
    const int r0 = strip * 11;
    const int Rv = (strip == 2) ? 10 : 11;
    if (t < 240) {
        #pragma unroll
        for (int j = 0; j < 21; ++j) {
            if (j < Rv + 10) {
                float2 v = *(const float2*)&st[((r0 + j) * SCW + c) * 2];
                w0r[j] = v.x; w1r[j] = v.y;
                wer[j] = sm[(r0 + j) * SMS + c];
            }
        }
    }
    __syncthreads();          // all st reads done; safe to overwrite via sv alias

    if (t < 240) {
        #pragma unroll
        for (int i = 0; i < 11; ++i) {
            if (i < Rv) {
                float tx0 = w0r[i + 5], tx1 = w1r[i + 5];
                float remx = fast_rcp(wer[i + 5]);
                float a0 = 0.f, a1 = 0.f;
                #pragma unroll
                for (int d = 0; d <= 2 * MU; ++d) {
                    float y0 = w0r[i + d], y1 = w1r[i + d], ey = wer[i + d];
                    float s = fast_rcp(fmaf(ey, remx, 1.f));    // (tanh(my-mx)+1)/2
                    float w = s * fmaf(tx0, y0, tx1 * y1);
                    a0 = fmaf(y0, w, a0);
                    a1 = fmaf(y1, w, a1);
                }
                float n2 = fmaf(a0, a0, a1 * a1);
                float inv = (n2 == 0.f) ? 1.f : fast_rsq(n2);
                sv0[(r0 + i) * SVS + c] = a0 * inv;
                sv1[(r0 + i) * SVS + c] = a1 * inv;
            }
        }
    }
    __syncthreads();

    // ---- H phase: lane<->row map (r = t&31, colgroup = t>>5 of 8 cols).
    // 18-value register window; odd strides make consecutive-r reads bank-free.
    float h0r[18], h1r[18], her[18];
    const int r = t & 31;
    const int cg = t >> 5;
    const int cbase = 8 + cg * 8;            // staged col of first center
    #pragma unroll
    for (int j = 0; j < 18; ++j) {
        int sc = cbase - 5 + j;              // 3..76: always in [0,80)
        h0r[j] = sv0[r * SVS + sc];
        h1r[j] = sv1[r * SVS + sc];
        her[j] = sm[(r + MU) * SMS + sc];
    }
    __syncthreads();          // all sv reads done; safe to overwrite below

    float o0[8], o1[8];
    #pragma unroll
    for (int k = 0; k < 8; ++k) {
        float tx0 = h0r[k + 5], tx1 = h1r[k + 5];
        float remx = fast_rcp(her[k + 5]);
        float a0 = 0.f, a1 = 0.f;
        #pragma unroll
        for (int d = 0; d <= 2 * MU; ++d) {
            float y0 = h0r[k + d], y1 = h1r[k + d], ey = her[k + d];
            float s = fast_rcp(fmaf(ey, remx, 1.f));
            float w = s * fmaf(tx0, y0, tx1 * y1);
            a0 = fmaf(y0, w, a0);
            a1 = fmaf(y1, w, a1);
        }
        float n2 = fmaf(a0, a0, a1 * a1);
        float inv = (n2 == 0.f) ? 1.f : fast_rsq(n2);
        o0[k] = a0 * inv;
        o1[k] = a1 * inv;
    }
    // write H results back into sv planes (cols 8..71) for coalesced output
    #pragma unroll
    for (int k = 0; k < 8; ++k) {
        sv0[r * SVS + cbase + k] = o0[k];
        sv1[r * SVS + cbase + k] = o1[k];
    }
    __syncthreads();

    // ---- coalesced global writeout (lanes along cols)
    #pragma unroll
    for (int m = 0; m < 8; ++m) {
        int px = t + 256 * m;
        int rr = px >> 6, cc = px & 63;
        float v0 = sv0[rr * SVS + 8 + cc];
        float v1 = sv1[rr * SVS + 8 + cc];
        size_t gi = (size_t)(h0 + rr) * WW + (w0 + cc);
        if (PLANAR_OUT) {
            tout[(size_t)(2 * b)     * plane + gi] = v0;
            tout[(size_t)(2 * b + 1) * plane + gi] = v1;
        } else {
            *(float2*)&tout[2 * ((size_t)b * plane + gi)] = make_float2(v0, v1);
        }
    }
}

extern "C" void kernel_launch(void* const* d_in, const int* in_sizes, int n_in,
                              void* d_out, int out_size, void* d_ws, size_t ws_size,
                              hipStream_t stream)
{
    const float* x = (const float*)d_in[0];   // (2,1,1024,1024) fp32
    char* ws = (char*)d_ws;
    const size_t plane = (size_t)HH * WW;

    float* tfA  = (float*)ws;                                           // 16 MB interleaved
    float* tfB  = (float*)(ws + sizeof(float) * BB * 2 * plane);        // 16 MB interleaved
    float* mag  = (float*)(ws + sizeof(float) * BB * 4 * plane);        // 8 MB raw
    float* gmax = (float*)(ws + sizeof(float) * BB * 6 * plane);        // 4 B
    float* block_max = gmax + 16;                                       // 1024 floats

    sobel_init<<<dim3(4, 128, BB), 256, 0, stream>>>(x, tfA, mag, block_max);
    reduce_max<<<1, 256, 0, stream>>>(block_max, gmax);

    dim3 g(WW / TW, HH / TH, BB);
    etf_vh<0><<<g, 256, 0, stream>>>(tfA, tfB, mag, gmax);
    etf_vh<0><<<g, 256, 0, stream>>>(tfB, tfA, mag, gmax);
    etf_vh<1><<<g, 256, 0, stream>>>(tfA, (float*)d_out, mag, gmax);
}

// Round 7
// 131.745 us; speedup vs baseline: 1.2661x; 1.0209x over previous
//
#include <hip/hip_runtime.h>

#define BB 2
#define HH 1024
#define WW 1024
#define MU 5

// fused-pass tile geometry
#define TH 32
#define TW 64
#define SH (TH + 2 * MU)   // 42 staged rows
#define SCW 80             // staged cols = TW + 16 (8-col halo each side)
#define SMS 83             // em LDS row stride (odd -> conflict-free H reads)
#define SVS 81             // V-result LDS row stride (odd -> conflict-free H reads)

__device__ __forceinline__ float fast_rcp(float x) { return __builtin_amdgcn_rcpf(x); }
__device__ __forceinline__ float fast_rsq(float x) { return __builtin_amdgcn_rsqf(x); }

// ---------------------------------------------------------------------------
// Kernel 1: Sobel + init tangent (interleaved (B,H,W,2)) + raw mag + block max.
// ---------------------------------------------------------------------------
#define SR 8
__global__ __launch_bounds__(256) void sobel_init(
    const float* __restrict__ x,
    float* __restrict__ tf,          // (B,H,W,2) interleaved
    float* __restrict__ mag,         // (B,H,W) raw
    float* __restrict__ block_max)   // 1024
{
    __shared__ float xs[SR + 2][264];
    const int t = threadIdx.x;
    const int w0 = blockIdx.x * 256;
    const int h0 = blockIdx.y * SR;
    const int b = blockIdx.z;
    const size_t plane = (size_t)HH * WW;
    const float* xb = x + (size_t)b * plane;

    for (int i = t; i < (SR + 2) * 66; i += 256) {
        int r = i / 66, c4 = i % 66;
        int g = h0 - 1 + r;
        int gw = w0 - 4 + 4 * c4;
        float4 v = make_float4(0.f, 0.f, 0.f, 0.f);
        if (g >= 0 && g < HH && gw >= 0 && gw < WW)
            v = *(const float4*)(xb + (size_t)g * WW + gw);
        *(float4*)&xs[r][4 * c4] = v;
    }
    __syncthreads();

    float lmax = 0.f;
    const int c = 4 + t;
    #pragma unroll
    for (int k = 0; k < SR; ++k) {
        const float* rT = xs[k], * rM = xs[k + 1], * rB = xs[k + 2];
        float tl = rT[c - 1], tc = rT[c], tr = rT[c + 1];
        float ml = rM[c - 1],             mr = rM[c + 1];
        float bl = rB[c - 1], bc = rB[c], br = rB[c + 1];
        float s0 = (bl - tl) + 2.f * (bc - tc) + (br - tr);   // k
        float s1 = (tr - tl) + 2.f * (mr - ml) + (br - bl);   // k^T
        float m = sqrtf(fmaf(s0, s0, s1 * s1));
        float inv = (m == 0.f) ? 1.f : fast_rcp(m);
        size_t gi = (size_t)(h0 + k) * WW + (w0 + t);
        mag[(size_t)b * plane + gi] = m;
        ((float2*)tf)[(size_t)b * plane + gi] = make_float2(-s1 * inv, s0 * inv);
        lmax = fmaxf(lmax, m);
    }

    #pragma unroll
    for (int off = 32; off; off >>= 1) lmax = fmaxf(lmax, __shfl_down(lmax, off, 64));
    __shared__ float smax[4];
    if ((t & 63) == 0) smax[t >> 6] = lmax;
    __syncthreads();
    if (t == 0)
        block_max[(blockIdx.z * 128 + blockIdx.y) * 4 + blockIdx.x] =
            fmaxf(fmaxf(smax[0], smax[1]), fmaxf(smax[2], smax[3]));
}

// ---------------------------------------------------------------------------
// Kernel 2: reduce 1024 per-block maxes -> gmax.
// ---------------------------------------------------------------------------
__global__ __launch_bounds__(256) void reduce_max(
    const float* __restrict__ block_max, float* __restrict__ gmax)
{
    const int t = threadIdx.x;
    float m = 0.f;
    #pragma unroll
    for (int i = 0; i < 4; ++i) m = fmaxf(m, block_max[t + 256 * i]);
    #pragma unroll
    for (int off = 32; off; off >>= 1) m = fmaxf(m, __shfl_down(m, off, 64));
    __shared__ float smax[4];
    if ((t & 63) == 0) smax[t >> 6] = m;
    __syncthreads();
    if (t == 0) gmax[0] = fmaxf(fmaxf(smax[0], smax[1]), fmaxf(smax[2], smax[3]));
}

// ---------------------------------------------------------------------------
// Kernel 3: FUSED V+H ETF pass, register sliding windows, REGISTER-FRUGAL:
//  - ONE window array set (r0a/r1a/rea[21]) reused by V (21) and H (18) phases
//    so their liveness never overlaps -> fits the 128-VGPR cap of
//    __launch_bounds__(256,4) without scratch spills (R6 lesson).
//  - H phase writes results straight to LDS after its load barrier (no o0/o1).
// Weight identity: (tanh(my-mx)+1)/2 = 1/(1 + em_y/em_x), em = exp(-2*mag/max),
// computed during staging from RAW mag.
// LDS 40824 B -> 4 blocks/CU. OOB staging: tang=0, em=1 (exact zero-pad).
// ---------------------------------------------------------------------------
template <int PLANAR_OUT>
__global__ __launch_bounds__(256, 4) void etf_vh(
    const float* __restrict__ tin,   // (B,H,W,2) interleaved
    float* __restrict__ tout,        // interleaved, or planar (B,2,H,W)
    const float* __restrict__ mag,   // (B,H,W) RAW
    const float* __restrict__ gmax)
{
    __shared__ float lds[SH * SCW * 2 + SH * SMS];   // 40824 B
    float* st  = lds;                 // staged tang, float2/px, row stride 160 floats
    float* sm  = lds + SH * SCW * 2;  // staged em, row stride SMS
    float* sv0 = lds;                 // V results plane 0 (aliases st)
    float* sv1 = lds + TH * SVS;      // V results plane 1

    const int t = threadIdx.x;
    const int w0 = blockIdx.x * TW;
    const int h0 = blockIdx.y * TH;
    const int b = blockIdx.z;
    const size_t plane = (size_t)HH * WW;
    const float* tb = tin + 2 * (size_t)b * plane;
    const float* mb = mag + (size_t)b * plane;
    const float s2 = 2.f * fast_rcp(gmax[0]);

    // ---- stage: tang 42x40 float4 (2px) chunks; em 42x20 float4 (4px) + exp
    for (int i = t; i < SH * 40 + SH * 20; i += 256) {
        if (i < SH * 40) {
            int r = i / 40, c4 = i % 40;
            int g = h0 - MU + r;
            int gw = w0 - 8 + 2 * c4;
            float4 v = make_float4(0.f, 0.f, 0.f, 0.f);
            if (g >= 0 && g < HH && gw >= 0 && gw < WW)
                v = *(const float4*)(tb + 2 * ((size_t)g * WW + gw));
            *(float4*)&st[r * (SCW * 2) + 4 * c4] = v;    // 16B-aligned
        } else {
            int j = i - SH * 40;
            int r = j / 20, c4 = j % 20;
            int g = h0 - MU + r;
            int gw = w0 - 8 + 4 * c4;
            float4 v = make_float4(0.f, 0.f, 0.f, 0.f);   // mag=0 -> em=1
            if (g >= 0 && g < HH && gw >= 0 && gw < WW)
                v = *(const float4*)(mb + (size_t)g * WW + gw);
            float* dst = &sm[r * SMS + 4 * c4];
            dst[0] = __expf(-s2 * v.x);
            dst[1] = __expf(-s2 * v.y);
            dst[2] = __expf(-s2 * v.z);
            dst[3] = __expf(-s2 * v.w);
        }
    }
    __syncthreads();

    // ---- shared register window (reused by V then H phase)
    float r0a[21], r1a[21], rea[21];

    // ---- V phase: 240 threads = 80 cols x 3 row-strips {11,11,10}.
    const int c = t % 80;
    const int strip = t / 80;
    const int vr0row = strip * 11;
    const int Rv = (strip == 2) ? 10 : 11;
    if (t < 240) {
        #pragma unroll
        for (int j = 0; j < 21; ++j) {
            if (j < Rv + 10) {
                float2 v = *(const float2*)&st[((vr0row + j) * SCW + c) * 2];
                r0a[j] = v.x; r1a[j] = v.y;
                rea[j] = sm[(vr0row + j) * SMS + c];
            }
        }
    }
    __syncthreads();          // all st reads done; safe to overwrite via sv alias

    if (t < 240) {
        #pragma unroll
        for (int i = 0; i < 11; ++i) {
            if (i < Rv) {
                float tx0 = r0a[i + 5], tx1 = r1a[i + 5];
                float remx = fast_rcp(rea[i + 5]);
                float a0 = 0.f, a1 = 0.f;
                #pragma unroll
                for (int d = 0; d <= 2 * MU; ++d) {
                    float y0 = r0a[i + d], y1 = r1a[i + d], ey = rea[i + d];
                    float s = fast_rcp(fmaf(ey, remx, 1.f));    // (tanh(my-mx)+1)/2
                    float w = s * fmaf(tx0, y0, tx1 * y1);
                    a0 = fmaf(y0, w, a0);
                    a1 = fmaf(y1, w, a1);
                }
                float n2 = fmaf(a0, a0, a1 * a1);
                float inv = (n2 == 0.f) ? 1.f : fast_rsq(n2);
                sv0[(vr0row + i) * SVS + c] = a0 * inv;
                sv1[(vr0row + i) * SVS + c] = a1 * inv;
            }
        }
    }
    __syncthreads();

    // ---- H phase: lane<->row map (r = t&31, colgroup = t>>5 of 8 cols).
    // Reuse r0a/r1a/rea[0..17] as the 18-value window.
    const int r = t & 31;
    const int cg = t >> 5;
    const int cbase = 8 + cg * 8;            // staged col of first center
    #pragma unroll
    for (int j = 0; j < 18; ++j) {
        int sc = cbase - 5 + j;              // 3..76: always in [0,80)
        r0a[j] = sv0[r * SVS + sc];
        r1a[j] = sv1[r * SVS + sc];
        rea[j] = sm[(r + MU) * SMS + sc];
    }
    __syncthreads();          // all sv reads done; safe to overwrite below

    #pragma unroll
    for (int k = 0; k < 8; ++k) {
        float tx0 = r0a[k + 5], tx1 = r1a[k + 5];
        float remx = fast_rcp(rea[k + 5]);
        float a0 = 0.f, a1 = 0.f;
        #pragma unroll
        for (int d = 0; d <= 2 * MU; ++d) {
            float y0 = r0a[k + d], y1 = r1a[k + d], ey = rea[k + d];
            float s = fast_rcp(fmaf(ey, remx, 1.f));
            float w = s * fmaf(tx0, y0, tx1 * y1);
            a0 = fmaf(y0, w, a0);
            a1 = fmaf(y1, w, a1);
        }
        float n2 = fmaf(a0, a0, a1 * a1);
        float inv = (n2 == 0.f) ? 1.f : fast_rsq(n2);
        sv0[r * SVS + cbase + k] = a0 * inv;    // write directly (post-barrier)
        sv1[r * SVS + cbase + k] = a1 * inv;
    }
    __syncthreads();

    // ---- coalesced global writeout (lanes along cols)
    #pragma unroll
    for (int m = 0; m < 8; ++m) {
        int px = t + 256 * m;
        int rr = px >> 6, cc = px & 63;
        float v0 = sv0[rr * SVS + 8 + cc];
        float v1 = sv1[rr * SVS + 8 + cc];
        size_t gi = (size_t)(h0 + rr) * WW + (w0 + cc);
        if (PLANAR_OUT) {
            tout[(size_t)(2 * b)     * plane + gi] = v0;
            tout[(size_t)(2 * b + 1) * plane + gi] = v1;
        } else {
            *(float2*)&tout[2 * ((size_t)b * plane + gi)] = make_float2(v0, v1);
        }
    }
}

extern "C" void kernel_launch(void* const* d_in, const int* in_sizes, int n_in,
                              void* d_out, int out_size, void* d_ws, size_t ws_size,
                              hipStream_t stream)
{
    const float* x = (const float*)d_in[0];   // (2,1,1024,1024) fp32
    char* ws = (char*)d_ws;
    const size_t plane = (size_t)HH * WW;

    float* tfA  = (float*)ws;                                           // 16 MB interleaved
    float* tfB  = (float*)(ws + sizeof(float) * BB * 2 * plane);        // 16 MB interleaved
    float* mag  = (float*)(ws + sizeof(float) * BB * 4 * plane);        // 8 MB raw
    float* gmax = (float*)(ws + sizeof(float) * BB * 6 * plane);        // 4 B
    float* block_max = gmax + 16;                                       // 1024 floats

    sobel_init<<<dim3(4, 128, BB), 256, 0, stream>>>(x, tfA, mag, block_max);
    reduce_max<<<1, 256, 0, stream>>>(block_max, gmax);

    dim3 g(WW / TW, HH / TH, BB);
    etf_vh<0><<<g, 256, 0, stream>>>(tfA, tfB, mag, gmax);
    etf_vh<0><<<g, 256, 0, stream>>>(tfB, tfA, mag, gmax);
    etf_vh<1><<<g, 256, 0, stream>>>(tfA, (float*)d_out, mag, gmax);
}